// Round 5
// baseline (362.825 us; speedup 1.0000x reference)
//
#include <hip/hip_runtime.h>

typedef _Float16 f16;
typedef __attribute__((ext_vector_type(8))) _Float16 f16x8;
typedef __attribute__((ext_vector_type(4))) _Float16 f16x4;
typedef __attribute__((ext_vector_type(4))) float    f32x4;

#define B_ROWS 16384
#define MPAD   17408   // 16384 + 8 clusters * 128-row tile padding
#define MTILES 136
#define NBLK   64      // B_ROWS / 256

typedef __attribute__((address_space(1))) void as1_void;
typedef __attribute__((address_space(3))) void as3_void;

__device__ __forceinline__ void gl_lds16(const void* g, void* l) {
    __builtin_amdgcn_global_load_lds((const as1_void*)g, (as3_void*)l, 16, 0, 0);
}

// ---------------- prep: rowmap init + per-block histogram + bias concat + zerobuf ----------------

__global__ __launch_bounds__(256) void k_prep(const int* __restrict__ lbl, int* __restrict__ blockhist,
                                              int* __restrict__ rowmap,
                                              const float* __restrict__ mb_, const float* __restrict__ lb_,
                                              float* __restrict__ bz, f16* __restrict__ zerob) {
    int b = blockIdx.x, t = threadIdx.x;
    int i = b * 256 + t;               // grid = 68 blocks -> MPAD exactly
    rowmap[i] = -1;
    if (b < NBLK) {
        __shared__ int h[8];
        if (t < 8) h[t] = 0;
        __syncthreads();
        atomicAdd(&h[lbl[i]], 1);      // LDS atomic
        __syncthreads();
        if (t < 8) blockhist[b * 8 + t] = h[t];
    } else if (b == NBLK) {
        if (t < 64) zerob[t] = (f16)0.f;       // 128 B of zeros
        if (t < 64) bz[t] = mb_[t];
        else if (t < 128) bz[t] = lb_[t - 64];
    }
}

// single block: cluster totals -> padded offsets, tile->cluster map, per-block bases
__global__ void k_offsets(const int* __restrict__ blockhist, int* offs, int* tilec, int* blockbase) {
    __shared__ int tot[8];
    __shared__ int so[9];
    int t = threadIdx.x;
    if (t < 8) {
        int s = 0;
        for (int b = 0; b < NBLK; ++b) s += blockhist[b * 8 + t];
        tot[t] = s;
    }
    __syncthreads();
    if (t == 0) {
        int o = 0;
        for (int c = 0; c < 8; ++c) { so[c] = o; o += (tot[c] + 127) & ~127; }
        so[8] = o;
        for (int c = 0; c < 9; ++c) offs[c] = so[c];
    }
    __syncthreads();
    if (t < 8) {
        int run = so[t];
        for (int b = 0; b < NBLK; ++b) {
            blockbase[b * 8 + t] = run;
            run += blockhist[b * 8 + t];
        }
    }
    if (t < MTILES) {
        int row = t * 128, c = 7;
        for (int cc = 0; cc < 8; ++cc)
            if (row >= so[cc] && row < so[cc + 1]) c = cc;
        tilec[t] = c;
    }
}

// scatter: LDS cursors seeded from per-block base — zero contended global atomics
__global__ __launch_bounds__(256) void k_scatter(const int* __restrict__ lbl,
                                                 const int* __restrict__ blockbase,
                                                 int* __restrict__ rowmap) {
    __shared__ int cur[8];
    if (threadIdx.x < 8) cur[threadIdx.x] = blockbase[blockIdx.x * 8 + threadIdx.x];
    __syncthreads();
    int i = blockIdx.x * 256 + threadIdx.x;
    int c = lbl[i];
    int pos = atomicAdd(&cur[c], 1);   // LDS atomic
    rowmap[pos] = i;
}

// ---------------- merged convert + 9 weight transposes — PERSISTENT grid-stride ----------------
// The command processor dispatches ~135 workgroups/us; the previous 5808-block version was
// launch-rate-bound (43 us for 81 MB of traffic at VALU 3%).  512 persistent blocks loop over
// virtual blocks instead.  Bodies unchanged from round 4.

struct Seg { const float* s; f16* d; int K, N, b0, nx, ny; long sCS, dCS; };
struct SegTab { Seg g[10]; };

__global__ __launch_bounds__(256) void k_trans(SegTab tab, const float* __restrict__ x,
                                               f16* __restrict__ xh, int nvb) {
    int t = threadIdx.x;
    __shared__ float ld[64][64];
    for (int vb = blockIdx.x; vb < nvb; vb += gridDim.x) {
        if (vb < tab.g[1].b0) {            // cvt segment: 8 f16 per thread
            size_t i = (size_t)vb * 256 + t;
            float4 a = ((const float4*)x)[2 * i];
            float4 b = ((const float4*)x)[2 * i + 1];
            f16x8 o = {(f16)a.x, (f16)a.y, (f16)a.z, (f16)a.w,
                       (f16)b.x, (f16)b.y, (f16)b.z, (f16)b.w};
            ((f16x8*)xh)[i] = o;
            continue;                       // block-uniform: no barrier divergence
        }
        int s = 9;
        while (vb < tab.g[s].b0) --s;      // block-uniform linear search
        Seg sg = tab.g[s];
        int lb = vb - sg.b0;
        int nxy = sg.nx * sg.ny;
        int z = lb / nxy; int r = lb - z * nxy;
        int by = r / sg.nx; int bx = r - by * sg.nx;
        const float* src = sg.s + (size_t)z * sg.sCS;
        f16* dst = sg.d + (size_t)z * sg.dCS;
        int n0 = bx * 64, k0 = by * 64;
        // read: float4 per thread, 4 passes of 16 rows, 16B-granule XOR swizzle
        int cr = t >> 4, cc = (t & 15) * 4;
        #pragma unroll
        for (int i = 0; i < 4; ++i) {
            int rr = cr + 16 * i;
            float4 v = *(const float4*)(src + (size_t)(k0 + rr) * sg.N + n0 + cc);
            *(float4*)&ld[rr][(((cc >> 2) ^ (rr & 15)) << 2)] = v;
        }
        __syncthreads();
        // write: granule G = p*256 + t; n = G>>3 (out row), gg = G&7 (16B k-granule)
        #pragma unroll
        for (int p = 0; p < 2; ++p) {
            int G = p * 256 + t;
            int n = G >> 3, gg = G & 7;
            f16x8 o;
            #pragma unroll
            for (int j = 0; j < 8; ++j) {
                int kk = gg * 8 + j;
                o[j] = (f16)ld[kk][(((n >> 2) ^ (kk & 15)) << 2) | (n & 3)];
            }
            *(f16x8*)(dst + (size_t)(n0 + n) * sg.K + k0 + gg * 8) = o;
        }
        __syncthreads();                    // ld[] reused next virtual block
    }
}

// ---------------- gemm2: 128x256 tile, BK=32, 512 threads, counted vmcnt -----------------------
// Higher arithmetic intensity: 2.1 MFLOP per 24 KB staged (87 FLOP/B vs 64 at 128x128) —
// attacks the measured ~10.4 B/cyc/CU ingest wall directly.  Grid must be 544 (N=1024 only).
// 8 waves as 2(M) x 4(N) of 64x64; acc 16 f32x4 = 64 VGPR; __launch_bounds__(512,4) caps at 128.
// LDS: 2 x (A 8KB + B 16KB) = 48 KB static; granule swizzle slot = sg ^ ((row>>1)&3) (R3-proven).
// RELU hardcoded (both users are relu layers).

template<int GATHER, int PERW>
__global__ __launch_bounds__(512, 4) void gemm2_k(
    const f16* __restrict__ A, const f16* __restrict__ Wt,
    const float* __restrict__ bias, f16* __restrict__ Out,
    const int* __restrict__ rowmap, const int* __restrict__ tilec,
    const f16* __restrict__ zerobuf, int K, int N)
{
    __shared__ __align__(16) char smem[49152];
    const int tid  = threadIdx.x;
    const int wave = tid >> 6;
    const int lane = tid & 63;

    const int id  = blockIdx.x;            // grid = 544
    const int xcd = id & 7;
    const int jj  = id >> 3;
    const int tm  = (jj % 17) * 8 + xcd;   // 0..135
    const int tn  = jj / 17;               // 0..3
    const int r0 = tm * 128, n0 = tn * 256;

    const f16* wb = Wt;
    const float* bb = bias;
    if (PERW) {
        int c = tilec[tm];
        wb += (size_t)c * K * N;
        bb += (size_t)c * N;
    }

    // staging map: srow = tid>>2 (0..127), sg = tid&3; source granule sg ^ ((row>>1)&3)
    const int srow = tid >> 2, sg = tid & 3;
    const int xk16 = (sg ^ ((srow >> 1) & 3)) * 16;
    const size_t rowB = (size_t)K * 2;

    const char* pa; size_t stepA;
    if (GATHER) {
        int g = rowmap[r0 + srow];
        if (g >= 0) { pa = (const char*)A + (size_t)g * rowB + xk16; stepA = 64; }
        else        { pa = (const char*)zerobuf;                     stepA = 0;  }
    } else {
        pa = (const char*)A + (size_t)(r0 + srow) * rowB + xk16; stepA = 64;
    }
    const char* pb = (const char*)wb + (size_t)(n0 + srow) * rowB + xk16;
    const size_t pbOff = 128 * rowB;       // key((srow+128)>>1 &3) == key(srow) since 64 % 4 == 0

    const int mb = (wave >> 2) * 64;       // 0 / 64
    const int nb = (wave & 3) * 64;        // 0..192
    const int quad = lane >> 4;
    const int r16  = lane & 15;
    const int off  = (quad ^ ((r16 >> 1) & 3)) * 16;

    float bv[4];
    #pragma unroll
    for (int j = 0; j < 4; ++j) bv[j] = bb[n0 + nb + j * 16 + r16];

    f32x4 acc[4][4];
    #pragma unroll
    for (int i = 0; i < 4; ++i)
        #pragma unroll
        for (int j = 0; j < 4; ++j)
            acc[i][j] = (f32x4){0.f, 0.f, 0.f, 0.f};

    auto stage = [&](char* dst) {
        gl_lds16(pa,           dst +         wave * 1024);   // A rows 0..127
        gl_lds16(pb,           dst + 8192  + wave * 1024);   // B rows 0..127
        gl_lds16(pb + pbOff,   dst + 16384 + wave * 1024);   // B rows 128..255
        pa += stepA; pb += 64;
    };

    auto compute = [&](const char* base) {
        const char* lA = base;             // [128][64B]
        const char* lB = base + 8192;      // [256][64B]
        f16x8 af[4], bf[4];
        #pragma unroll
        for (int i = 0; i < 4; ++i)
            af[i] = *(const f16x8*)(lA + (mb + i * 16 + r16) * 64 + off);
        #pragma unroll
        for (int j = 0; j < 4; ++j)
            bf[j] = *(const f16x8*)(lB + (nb + j * 16 + r16) * 64 + off);
        #pragma unroll
        for (int i = 0; i < 4; ++i)
            #pragma unroll
            for (int j = 0; j < 4; ++j)
                acc[i][j] = __builtin_amdgcn_mfma_f32_16x16x32_f16(af[i], bf[j], acc[i][j], 0, 0, 0);
    };

    const int nk = K >> 5;
    stage(smem);                            // prologue: 3 loads in flight
    int cur = 0;
    for (int kb = 0; kb < nk - 1; ++kb) {
        stage(smem + (cur ^ 1) * 24576);                   // +3 loads (next buffer)
        asm volatile("s_waitcnt vmcnt(3)" ::: "memory");   // own cur-buffer loads landed
        __builtin_amdgcn_s_barrier();                      // all waves' cur loads landed
        compute(smem + cur * 24576);
        __builtin_amdgcn_s_barrier();                      // cur fully read
        cur ^= 1;
    }
    asm volatile("s_waitcnt vmcnt(0)" ::: "memory");
    __builtin_amdgcn_s_barrier();
    compute(smem + cur * 24576);

    #pragma unroll
    for (int i = 0; i < 4; ++i) {
        #pragma unroll
        for (int r = 0; r < 4; ++r) {
            int orow = r0 + mb + i * 16 + quad * 4 + r;
            #pragma unroll
            for (int j = 0; j < 4; ++j) {
                int ocol = n0 + nb + j * 16 + r16;
                float v = fmaxf(acc[i][j][r] + bv[j], 0.f);
                Out[(size_t)orow * N + ocol] = (f16)v;
            }
        }
    }
}

// ---------------- MFMA GEMM: 128x128 tile, BK=64, counted vmcnt (round-4, unchanged) ----------

template<int GATHER, int PERW, int RELU, int EPI>
__global__ __launch_bounds__(256) void gemm_k(
    const f16* __restrict__ A, const f16* __restrict__ Wt,
    const float* __restrict__ bias, f16* __restrict__ Out, float* __restrict__ OutF,
    const float* __restrict__ eps,
    const int* __restrict__ rowmap, const int* __restrict__ tilec,
    const f16* __restrict__ zerobuf, int K, int N)
{
    __shared__ __align__(16) char smem[65536];   // 2 x (lA 16KB + lB 16KB)
    const int tid  = threadIdx.x;
    const int wave = tid >> 6;
    const int lane = tid & 63;

    const int id  = blockIdx.x;
    const int xcd = id & 7;
    const int jj  = id >> 3;
    const int tm  = (jj % 17) * 8 + xcd;   // 0..135
    const int tn  = jj / 17;
    const int r0 = tm * 128, n0 = tn * 128;

    const f16* wb = Wt;
    const float* bb = bias;
    if (PERW) {
        int c = tilec[tm];
        wb += (size_t)c * K * N;
        bb += (size_t)c * N;
    }

    const int srow = tid >> 3;             // 0..31
    const int sg   = tid & 7;              // 0..7
    const int xk16 = (sg ^ (srow & 7)) * 16;
    const size_t rowB = (size_t)K * 2;
    const size_t passB = 32 * rowB;

    const char* pa[4]; size_t stepA[4];
    #pragma unroll
    for (int p = 0; p < 4; ++p) {
        int gr = r0 + p * 32 + srow;
        if (GATHER) {
            int g = rowmap[gr];
            if (g >= 0) { pa[p] = (const char*)(A + (size_t)g * K) + xk16; stepA[p] = 128; }
            else        { pa[p] = (const char*)zerobuf;                    stepA[p] = 0;   }
        } else {
            pa[p] = (const char*)(A + (size_t)gr * K) + xk16; stepA[p] = 128;
        }
    }
    const char* pb = (const char*)(wb + (size_t)(n0 + srow) * K) + xk16;

    const int mb = (wave >> 1) * 64;
    const int nb = (wave & 1) * 64;
    const int quad = lane >> 4;
    const int r16  = lane & 15;
    const int key  = r16 & 7;

    float bv[4];
    #pragma unroll
    for (int j = 0; j < 4; ++j) bv[j] = bb[n0 + nb + j * 16 + r16];

    f32x4 acc[4][4];
    #pragma unroll
    for (int i = 0; i < 4; ++i)
        #pragma unroll
        for (int j = 0; j < 4; ++j)
            acc[i][j] = (f32x4){0.f, 0.f, 0.f, 0.f};

    auto stage = [&](char* dst) {
        #pragma unroll
        for (int p = 0; p < 4; ++p)
            gl_lds16(pa[p], dst + p * 4096 + wave * 1024);
        #pragma unroll
        for (int p = 0; p < 4; ++p)
            gl_lds16(pb + p * passB, dst + 16384 + p * 4096 + wave * 1024);
        #pragma unroll
        for (int p = 0; p < 4; ++p) pa[p] += stepA[p];
        pb += 128;
    };

    auto compute = [&](const char* base) {
        const char* lA = base;
        const char* lB = base + 16384;
        #pragma unroll
        for (int kk = 0; kk < 2; ++kk) {
            const int off = ((kk * 4 + quad) ^ key) * 16;
            f16x8 af[4], bf[4];
            #pragma unroll
            for (int i = 0; i < 4; ++i)
                af[i] = *(const f16x8*)(lA + (mb + i * 16 + r16) * 128 + off);
            #pragma unroll
            for (int j = 0; j < 4; ++j)
                bf[j] = *(const f16x8*)(lB + (nb + j * 16 + r16) * 128 + off);
            #pragma unroll
            for (int i = 0; i < 4; ++i)
                #pragma unroll
                for (int j = 0; j < 4; ++j)
                    acc[i][j] = __builtin_amdgcn_mfma_f32_16x16x32_f16(af[i], bf[j], acc[i][j], 0, 0, 0);
        }
    };

    const int nk = K >> 6;
    stage(smem);
    int cur = 0;
    for (int kb = 0; kb < nk - 1; ++kb) {
        stage(smem + ((cur ^ 1) << 15));
        asm volatile("s_waitcnt vmcnt(8)" ::: "memory");
        __builtin_amdgcn_s_barrier();
        compute(smem + (cur << 15));
        __builtin_amdgcn_s_barrier();
        cur ^= 1;
    }
    asm volatile("s_waitcnt vmcnt(0)" ::: "memory");
    __builtin_amdgcn_s_barrier();
    compute(smem + (cur << 15));

    if (EPI == 2) {
        __syncthreads();
        #pragma unroll
        for (int i = 0; i < 4; ++i) {
            #pragma unroll
            for (int r = 0; r < 4; ++r) {
                int lr = mb + i * 16 + quad * 4 + r;
                #pragma unroll
                for (int j = 0; j < 4; ++j) {
                    int lc = nb + j * 16 + r16;
                    float v = acc[i][j][r] + bv[j];
                    *(f16*)(smem + lr * 256 + ((((lc >> 3) ^ (lr & 7))) << 4) + ((lc & 7) << 1)) = (f16)v;
                }
            }
        }
        __syncthreads();
        const int col = tid & 63;
        const int rb  = tid >> 6;
        for (int rr = 0; rr < 32; ++rr) {
            int row = rb * 32 + rr;
            int g = rowmap[r0 + row];
            float e = (g >= 0) ? eps[(size_t)g * 64 + col] : 0.f;
            float mu = (float)*(const f16*)(smem + row * 256 + ((((col >> 3) ^ (row & 7))) << 4) + ((col & 7) << 1));
            int c2 = col + 64;
            float lv = (float)*(const f16*)(smem + row * 256 + ((((c2 >> 3) ^ (row & 7))) << 4) + ((c2 & 7) << 1));
            Out[(size_t)(r0 + row) * 64 + col] = (f16)(mu + expf(0.5f * lv) * e);
        }
        return;
    }

    #pragma unroll
    for (int i = 0; i < 4; ++i) {
        #pragma unroll
        for (int r = 0; r < 4; ++r) {
            int orow = r0 + mb + i * 16 + quad * 4 + r;
            int g = 0;
            if (EPI == 1) g = rowmap[orow];
            #pragma unroll
            for (int j = 0; j < 4; ++j) {
                int ocol = n0 + nb + j * 16 + r16;
                float v = acc[i][j][r] + bv[j];
                if (RELU) v = fmaxf(v, 0.f);
                if (EPI == 1) {
                    if (g >= 0) OutF[(size_t)g * N + ocol] = v;
                } else {
                    Out[(size_t)orow * N + ocol] = (f16)v;
                }
            }
        }
    }
}

// ---------------- launch ----------------

extern "C" void kernel_launch(void* const* d_in, const int* in_sizes, int n_in,
                              void* d_out, int out_size, void* d_ws, size_t ws_size,
                              hipStream_t stream) {
    const float* x      = (const float*)d_in[0];
    const int*   lbl    = (const int*)  d_in[1];
    const float* eps    = (const float*)d_in[2];
    const float* enc_W0 = (const float*)d_in[3];
    const float* enc_b0 = (const float*)d_in[4];
    const float* enc_Wu = (const float*)d_in[5];
    const float* enc_bu = (const float*)d_in[6];
    const float* enc_W2 = (const float*)d_in[7];
    const float* enc_b2 = (const float*)d_in[8];
    const float* mu_W   = (const float*)d_in[9];
    const float* mu_b   = (const float*)d_in[10];
    const float* lv_W   = (const float*)d_in[11];
    const float* lv_b   = (const float*)d_in[12];
    const float* dWu0   = (const float*)d_in[13];
    const float* dbu0   = (const float*)d_in[14];
    const float* dW1    = (const float*)d_in[15];
    const float* db1    = (const float*)d_in[16];
    const float* dWu2   = (const float*)d_in[17];
    const float* dbu2   = (const float*)d_in[18];
    const float* finW   = (const float*)d_in[19];
    const float* finb   = (const float*)d_in[20];
    float* out = (float*)d_out;
    (void)in_sizes; (void)n_in; (void)out_size; (void)ws_size;

    char* base = (char*)d_ws;
    size_t off = 0;
    auto alloc = [&](size_t bytes) { char* r = base + off; off = (off + bytes + 255) & ~(size_t)255; return r; };
    f16* xh     = (f16*)alloc((size_t)B_ROWS * 512 * 2);
    f16* buf1   = (f16*)alloc((size_t)MPAD * 1024 * 2);  // h1 / h6
    f16* buf2   = (f16*)alloc((size_t)MPAD * 512 * 2);   // h2 / h5
    f16* buf3   = (f16*)alloc((size_t)MPAD * 256 * 2);   // h3 / h4
    f16* zb     = (f16*)alloc((size_t)MPAD * 64 * 2);
    f16* w0t    = (f16*)alloc(1024ul * 512 * 2);
    f16* wut    = (f16*)alloc(8ul * 512 * 1024 * 2);
    f16* w2t    = (f16*)alloc(256ul * 512 * 2);
    f16* wzt    = (f16*)alloc(128ul * 256 * 2);
    f16* wd0t   = (f16*)alloc(8ul * 256 * 64 * 2);
    f16* wd1t   = (f16*)alloc(512ul * 256 * 2);
    f16* wd2t   = (f16*)alloc(8ul * 1024 * 512 * 2);
    f16* wft    = (f16*)alloc(8ul * 512 * 1024 * 2);
    float* bz   = (float*)alloc(128 * 4);
    int* rowmap = (int*)alloc(MPAD * 4);
    int* blockhist = (int*)alloc(NBLK * 8 * 4);
    int* blockbase = (int*)alloc(NBLK * 8 * 4);
    int* offs   = (int*)alloc(64);
    int* tilec  = (int*)alloc(MTILES * 4);
    f16* zerob  = (f16*)alloc(256);

    // cluster sort + bias concat
    k_prep<<<MPAD / 256, 256, 0, stream>>>(lbl, blockhist, rowmap, mu_b, lv_b, bz, zerob);
    k_offsets<<<1, 256, 0, stream>>>(blockhist, offs, tilec, blockbase);
    k_scatter<<<NBLK, 256, 0, stream>>>(lbl, blockbase, rowmap);

    // merged convert + transposes, persistent 512-block grid
    SegTab tab;
    int b0 = B_ROWS * 512 / 8 / 256;   // 4096 cvt virtual blocks
    auto seg = [&](int i, const float* s, f16* d, int K, int N, int nz, long sCS, long dCS) {
        int nx = N / 64, ny = K / 64;
        tab.g[i] = Seg{s, d, K, N, b0, nx, ny, sCS, dCS};
        b0 += nx * ny * nz;
    };
    tab.g[0] = Seg{nullptr, nullptr, 0, 0, 0, 0, 0, 0, 0};
    seg(1, enc_W0, w0t, 512, 1024, 1, 0, 0);
    seg(2, enc_Wu, wut, 1024, 512, 8, 1024l * 512, 512l * 1024);
    seg(3, enc_W2, w2t, 512, 256, 1, 0, 0);
    seg(4, mu_W, wzt, 256, 64, 1, 0, 0);
    seg(5, lv_W, wzt + 64 * 256, 256, 64, 1, 0, 0);
    seg(6, dWu0, wd0t, 64, 256, 8, 64l * 256, 256l * 64);
    seg(7, dW1, wd1t, 256, 512, 1, 0, 0);
    seg(8, dWu2, wd2t, 512, 1024, 8, 512l * 1024, 1024l * 512);
    seg(9, finW, wft, 1024, 512, 8, 1024l * 512, 512l * 1024);
    k_trans<<<512, 256, 0, stream>>>(tab, x, xh, b0);

    // encoder
    gemm2_k<1,0><<<MTILES * 4, 512, 0, stream>>>(xh,   w0t,  enc_b0, buf1, rowmap, tilec, zerob, 512, 1024);
    gemm_k<0,1,1,0><<<MTILES * 4, 256, 0, stream>>>(buf1, wut,  enc_bu, buf2, nullptr, nullptr, rowmap, tilec, zerob, 1024, 512);
    gemm_k<0,0,1,0><<<MTILES * 2, 256, 0, stream>>>(buf2, w2t,  enc_b2, buf3, nullptr, nullptr, rowmap, tilec, zerob, 512, 256);
    // latent heads (mu|logvar fused, no relu) + in-kernel reparameterize -> z
    gemm_k<0,0,0,2><<<MTILES * 1, 256, 0, stream>>>(buf3, wzt,  bz,     zb,   nullptr, eps,     rowmap, tilec, zerob, 256, 128);
    // decoder
    gemm_k<0,1,1,0><<<MTILES * 2, 256, 0, stream>>>(zb,   wd0t, dbu0,   buf3, nullptr, nullptr, rowmap, tilec, zerob, 64, 256);
    gemm_k<0,0,1,0><<<MTILES * 4, 256, 0, stream>>>(buf3, wd1t, db1,    buf2, nullptr, nullptr, rowmap, tilec, zerob, 256, 512);
    gemm2_k<0,1><<<MTILES * 4, 512, 0, stream>>>(buf2, wd2t, dbu2,   buf1, rowmap, tilec, zerob, 512, 1024);
    // final per-cluster layer, fp32 scatter to d_out
    gemm_k<0,1,0,1><<<MTILES * 4, 256, 0, stream>>>(buf1, wft,  finb,   nullptr, out,  nullptr, rowmap, tilec, zerob, 1024, 512);
}

// Round 6
// 356.913 us; speedup vs baseline: 1.0166x; 1.0166x over previous
//
#include <hip/hip_runtime.h>

typedef _Float16 f16;
typedef __attribute__((ext_vector_type(8))) _Float16 f16x8;
typedef __attribute__((ext_vector_type(4))) _Float16 f16x4;
typedef __attribute__((ext_vector_type(4))) float    f32x4;

#define B_ROWS 16384
#define MPAD   17408   // 16384 + 8 clusters * 128-row tile padding
#define MTILES 136
#define NBLK   64      // B_ROWS / 256

typedef __attribute__((address_space(1))) void as1_void;
typedef __attribute__((address_space(3))) void as3_void;

__device__ __forceinline__ void gl_lds16(const void* g, void* l) {
    __builtin_amdgcn_global_load_lds((const as1_void*)g, (as3_void*)l, 16, 0, 0);
}

// non-temporal store: no write-allocate, no L2/L3 pollution — for single-use outputs
template<typename T>
__device__ __forceinline__ void st_nt(T* p, T v) { __builtin_nontemporal_store(v, p); }

// ---------------- prep: rowmap init + per-block histogram + bias concat + zerobuf ----------------

__global__ __launch_bounds__(256) void k_prep(const int* __restrict__ lbl, int* __restrict__ blockhist,
                                              int* __restrict__ rowmap,
                                              const float* __restrict__ mb_, const float* __restrict__ lb_,
                                              float* __restrict__ bz, f16* __restrict__ zerob) {
    int b = blockIdx.x, t = threadIdx.x;
    int i = b * 256 + t;               // grid = 68 blocks -> MPAD exactly
    rowmap[i] = -1;
    if (b < NBLK) {
        __shared__ int h[8];
        if (t < 8) h[t] = 0;
        __syncthreads();
        atomicAdd(&h[lbl[i]], 1);      // LDS atomic
        __syncthreads();
        if (t < 8) blockhist[b * 8 + t] = h[t];
    } else if (b == NBLK) {
        if (t < 64) zerob[t] = (f16)0.f;       // 128 B of zeros
        if (t < 64) bz[t] = mb_[t];
        else if (t < 128) bz[t] = lb_[t - 64];
    }
}

// single block: cluster totals -> padded offsets, tile->cluster map, per-block bases
__global__ void k_offsets(const int* __restrict__ blockhist, int* offs, int* tilec, int* blockbase) {
    __shared__ int tot[8];
    __shared__ int so[9];
    int t = threadIdx.x;
    if (t < 8) {
        int s = 0;
        for (int b = 0; b < NBLK; ++b) s += blockhist[b * 8 + t];
        tot[t] = s;
    }
    __syncthreads();
    if (t == 0) {
        int o = 0;
        for (int c = 0; c < 8; ++c) { so[c] = o; o += (tot[c] + 127) & ~127; }
        so[8] = o;
        for (int c = 0; c < 9; ++c) offs[c] = so[c];
    }
    __syncthreads();
    if (t < 8) {
        int run = so[t];
        for (int b = 0; b < NBLK; ++b) {
            blockbase[b * 8 + t] = run;
            run += blockhist[b * 8 + t];
        }
    }
    if (t < MTILES) {
        int row = t * 128, c = 7;
        for (int cc = 0; cc < 8; ++cc)
            if (row >= so[cc] && row < so[cc + 1]) c = cc;
        tilec[t] = c;
    }
}

// scatter: LDS cursors seeded from per-block base — zero contended global atomics
__global__ __launch_bounds__(256) void k_scatter(const int* __restrict__ lbl,
                                                 const int* __restrict__ blockbase,
                                                 int* __restrict__ rowmap) {
    __shared__ int cur[8];
    if (threadIdx.x < 8) cur[threadIdx.x] = blockbase[blockIdx.x * 8 + threadIdx.x];
    __syncthreads();
    int i = blockIdx.x * 256 + threadIdx.x;
    int c = lbl[i];
    int pos = atomicAdd(&cur[c], 1);   // LDS atomic
    rowmap[pos] = i;
}

// ---------------- merged convert + 9 weight transposes — PERSISTENT grid-stride ----------------
// xh is single-use per layer-1 -> NT store.  Transposed weights are re-read soon -> cached stores.

struct Seg { const float* s; f16* d; int K, N, b0, nx, ny; long sCS, dCS; };
struct SegTab { Seg g[10]; };

__global__ __launch_bounds__(256) void k_trans(SegTab tab, const float* __restrict__ x,
                                               f16* __restrict__ xh, int nvb) {
    int t = threadIdx.x;
    __shared__ float ld[64][64];
    for (int vb = blockIdx.x; vb < nvb; vb += gridDim.x) {
        if (vb < tab.g[1].b0) {            // cvt segment: 8 f16 per thread
            size_t i = (size_t)vb * 256 + t;
            float4 a = ((const float4*)x)[2 * i];
            float4 b = ((const float4*)x)[2 * i + 1];
            f16x8 o = {(f16)a.x, (f16)a.y, (f16)a.z, (f16)a.w,
                       (f16)b.x, (f16)b.y, (f16)b.z, (f16)b.w};
            st_nt(&((f16x8*)xh)[i], o);
            continue;                       // block-uniform: no barrier divergence
        }
        int s = 9;
        while (vb < tab.g[s].b0) --s;      // block-uniform linear search
        Seg sg = tab.g[s];
        int lb = vb - sg.b0;
        int nxy = sg.nx * sg.ny;
        int z = lb / nxy; int r = lb - z * nxy;
        int by = r / sg.nx; int bx = r - by * sg.nx;
        const float* src = sg.s + (size_t)z * sg.sCS;
        f16* dst = sg.d + (size_t)z * sg.dCS;
        int n0 = bx * 64, k0 = by * 64;
        // read: float4 per thread, 4 passes of 16 rows, 16B-granule XOR swizzle
        int cr = t >> 4, cc = (t & 15) * 4;
        #pragma unroll
        for (int i = 0; i < 4; ++i) {
            int rr = cr + 16 * i;
            float4 v = *(const float4*)(src + (size_t)(k0 + rr) * sg.N + n0 + cc);
            *(float4*)&ld[rr][(((cc >> 2) ^ (rr & 15)) << 2)] = v;
        }
        __syncthreads();
        // write: granule G = p*256 + t; n = G>>3 (out row), gg = G&7 (16B k-granule)
        #pragma unroll
        for (int p = 0; p < 2; ++p) {
            int G = p * 256 + t;
            int n = G >> 3, gg = G & 7;
            f16x8 o;
            #pragma unroll
            for (int j = 0; j < 8; ++j) {
                int kk = gg * 8 + j;
                o[j] = (f16)ld[kk][(((n >> 2) ^ (kk & 15)) << 2) | (n & 3)];
            }
            *(f16x8*)(dst + (size_t)(n0 + n) * sg.K + k0 + gg * 8) = o;
        }
        __syncthreads();                    // ld[] reused next virtual block
    }
}

// ---------------- gemm2: 128x256 tile, BK=32, 512 threads, counted vmcnt -----------------------
// (round-5 structure; epilogue stores now non-temporal)

template<int GATHER, int PERW>
__global__ __launch_bounds__(512, 4) void gemm2_k(
    const f16* __restrict__ A, const f16* __restrict__ Wt,
    const float* __restrict__ bias, f16* __restrict__ Out,
    const int* __restrict__ rowmap, const int* __restrict__ tilec,
    const f16* __restrict__ zerobuf, int K, int N)
{
    __shared__ __align__(16) char smem[49152];
    const int tid  = threadIdx.x;
    const int wave = tid >> 6;
    const int lane = tid & 63;

    const int id  = blockIdx.x;            // grid = 544
    const int xcd = id & 7;
    const int jj  = id >> 3;
    const int tm  = (jj % 17) * 8 + xcd;   // 0..135
    const int tn  = jj / 17;               // 0..3
    const int r0 = tm * 128, n0 = tn * 256;

    const f16* wb = Wt;
    const float* bb = bias;
    if (PERW) {
        int c = tilec[tm];
        wb += (size_t)c * K * N;
        bb += (size_t)c * N;
    }

    const int srow = tid >> 2, sg = tid & 3;
    const int xk16 = (sg ^ ((srow >> 1) & 3)) * 16;
    const size_t rowB = (size_t)K * 2;

    const char* pa; size_t stepA;
    if (GATHER) {
        int g = rowmap[r0 + srow];
        if (g >= 0) { pa = (const char*)A + (size_t)g * rowB + xk16; stepA = 64; }
        else        { pa = (const char*)zerobuf;                     stepA = 0;  }
    } else {
        pa = (const char*)A + (size_t)(r0 + srow) * rowB + xk16; stepA = 64;
    }
    const char* pb = (const char*)wb + (size_t)(n0 + srow) * rowB + xk16;
    const size_t pbOff = 128 * rowB;

    const int mb = (wave >> 2) * 64;       // 0 / 64
    const int nb = (wave & 3) * 64;        // 0..192
    const int quad = lane >> 4;
    const int r16  = lane & 15;
    const int off  = (quad ^ ((r16 >> 1) & 3)) * 16;

    float bv[4];
    #pragma unroll
    for (int j = 0; j < 4; ++j) bv[j] = bb[n0 + nb + j * 16 + r16];

    f32x4 acc[4][4];
    #pragma unroll
    for (int i = 0; i < 4; ++i)
        #pragma unroll
        for (int j = 0; j < 4; ++j)
            acc[i][j] = (f32x4){0.f, 0.f, 0.f, 0.f};

    auto stage = [&](char* dst) {
        gl_lds16(pa,           dst +         wave * 1024);   // A rows 0..127
        gl_lds16(pb,           dst + 8192  + wave * 1024);   // B rows 0..127
        gl_lds16(pb + pbOff,   dst + 16384 + wave * 1024);   // B rows 128..255
        pa += stepA; pb += 64;
    };

    auto compute = [&](const char* base) {
        const char* lA = base;             // [128][64B]
        const char* lB = base + 8192;      // [256][64B]
        f16x8 af[4], bf[4];
        #pragma unroll
        for (int i = 0; i < 4; ++i)
            af[i] = *(const f16x8*)(lA + (mb + i * 16 + r16) * 64 + off);
        #pragma unroll
        for (int j = 0; j < 4; ++j)
            bf[j] = *(const f16x8*)(lB + (nb + j * 16 + r16) * 64 + off);
        #pragma unroll
        for (int i = 0; i < 4; ++i)
            #pragma unroll
            for (int j = 0; j < 4; ++j)
                acc[i][j] = __builtin_amdgcn_mfma_f32_16x16x32_f16(af[i], bf[j], acc[i][j], 0, 0, 0);
    };

    const int nk = K >> 5;
    stage(smem);                            // prologue: 3 loads in flight
    int cur = 0;
    for (int kb = 0; kb < nk - 1; ++kb) {
        stage(smem + (cur ^ 1) * 24576);                   // +3 loads (next buffer)
        asm volatile("s_waitcnt vmcnt(3)" ::: "memory");   // own cur-buffer loads landed
        __builtin_amdgcn_s_barrier();                      // all waves' cur loads landed
        compute(smem + cur * 24576);
        __builtin_amdgcn_s_barrier();                      // cur fully read
        cur ^= 1;
    }
    asm volatile("s_waitcnt vmcnt(0)" ::: "memory");
    __builtin_amdgcn_s_barrier();
    compute(smem + cur * 24576);

    #pragma unroll
    for (int i = 0; i < 4; ++i) {
        #pragma unroll
        for (int r = 0; r < 4; ++r) {
            int orow = r0 + mb + i * 16 + quad * 4 + r;
            #pragma unroll
            for (int j = 0; j < 4; ++j) {
                int ocol = n0 + nb + j * 16 + r16;
                float v = fmaxf(acc[i][j][r] + bv[j], 0.f);
                st_nt(&Out[(size_t)orow * N + ocol], (f16)v);
            }
        }
    }
}

// ---------------- MFMA GEMM: 128x128 tile, BK=64, counted vmcnt (round-4 loop) -----------------
// Epilogue stores now non-temporal (single-use activations / final output).

template<int GATHER, int PERW, int RELU, int EPI>
__global__ __launch_bounds__(256) void gemm_k(
    const f16* __restrict__ A, const f16* __restrict__ Wt,
    const float* __restrict__ bias, f16* __restrict__ Out, float* __restrict__ OutF,
    const float* __restrict__ eps,
    const int* __restrict__ rowmap, const int* __restrict__ tilec,
    const f16* __restrict__ zerobuf, int K, int N)
{
    __shared__ __align__(16) char smem[65536];   // 2 x (lA 16KB + lB 16KB)
    const int tid  = threadIdx.x;
    const int wave = tid >> 6;
    const int lane = tid & 63;

    const int id  = blockIdx.x;
    const int xcd = id & 7;
    const int jj  = id >> 3;
    const int tm  = (jj % 17) * 8 + xcd;   // 0..135
    const int tn  = jj / 17;
    const int r0 = tm * 128, n0 = tn * 128;

    const f16* wb = Wt;
    const float* bb = bias;
    if (PERW) {
        int c = tilec[tm];
        wb += (size_t)c * K * N;
        bb += (size_t)c * N;
    }

    const int srow = tid >> 3;             // 0..31
    const int sg   = tid & 7;              // 0..7
    const int xk16 = (sg ^ (srow & 7)) * 16;
    const size_t rowB = (size_t)K * 2;
    const size_t passB = 32 * rowB;

    const char* pa[4]; size_t stepA[4];
    #pragma unroll
    for (int p = 0; p < 4; ++p) {
        int gr = r0 + p * 32 + srow;
        if (GATHER) {
            int g = rowmap[gr];
            if (g >= 0) { pa[p] = (const char*)(A + (size_t)g * K) + xk16; stepA[p] = 128; }
            else        { pa[p] = (const char*)zerobuf;                    stepA[p] = 0;   }
        } else {
            pa[p] = (const char*)(A + (size_t)gr * K) + xk16; stepA[p] = 128;
        }
    }
    const char* pb = (const char*)(wb + (size_t)(n0 + srow) * K) + xk16;

    const int mb = (wave >> 1) * 64;
    const int nb = (wave & 1) * 64;
    const int quad = lane >> 4;
    const int r16  = lane & 15;
    const int key  = r16 & 7;

    float bv[4];
    #pragma unroll
    for (int j = 0; j < 4; ++j) bv[j] = bb[n0 + nb + j * 16 + r16];

    f32x4 acc[4][4];
    #pragma unroll
    for (int i = 0; i < 4; ++i)
        #pragma unroll
        for (int j = 0; j < 4; ++j)
            acc[i][j] = (f32x4){0.f, 0.f, 0.f, 0.f};

    auto stage = [&](char* dst) {
        #pragma unroll
        for (int p = 0; p < 4; ++p)
            gl_lds16(pa[p], dst + p * 4096 + wave * 1024);
        #pragma unroll
        for (int p = 0; p < 4; ++p)
            gl_lds16(pb + p * passB, dst + 16384 + p * 4096 + wave * 1024);
        #pragma unroll
        for (int p = 0; p < 4; ++p) pa[p] += stepA[p];
        pb += 128;
    };

    auto compute = [&](const char* base) {
        const char* lA = base;
        const char* lB = base + 16384;
        #pragma unroll
        for (int kk = 0; kk < 2; ++kk) {
            const int off = ((kk * 4 + quad) ^ key) * 16;
            f16x8 af[4], bf[4];
            #pragma unroll
            for (int i = 0; i < 4; ++i)
                af[i] = *(const f16x8*)(lA + (mb + i * 16 + r16) * 128 + off);
            #pragma unroll
            for (int j = 0; j < 4; ++j)
                bf[j] = *(const f16x8*)(lB + (nb + j * 16 + r16) * 128 + off);
            #pragma unroll
            for (int i = 0; i < 4; ++i)
                #pragma unroll
                for (int j = 0; j < 4; ++j)
                    acc[i][j] = __builtin_amdgcn_mfma_f32_16x16x32_f16(af[i], bf[j], acc[i][j], 0, 0, 0);
        }
    };

    const int nk = K >> 6;
    stage(smem);
    int cur = 0;
    for (int kb = 0; kb < nk - 1; ++kb) {
        stage(smem + ((cur ^ 1) << 15));
        asm volatile("s_waitcnt vmcnt(8)" ::: "memory");
        __builtin_amdgcn_s_barrier();
        compute(smem + (cur << 15));
        __builtin_amdgcn_s_barrier();
        cur ^= 1;
    }
    asm volatile("s_waitcnt vmcnt(0)" ::: "memory");
    __builtin_amdgcn_s_barrier();
    compute(smem + (cur << 15));

    if (EPI == 2) {
        __syncthreads();
        #pragma unroll
        for (int i = 0; i < 4; ++i) {
            #pragma unroll
            for (int r = 0; r < 4; ++r) {
                int lr = mb + i * 16 + quad * 4 + r;
                #pragma unroll
                for (int j = 0; j < 4; ++j) {
                    int lc = nb + j * 16 + r16;
                    float v = acc[i][j][r] + bv[j];
                    *(f16*)(smem + lr * 256 + ((((lc >> 3) ^ (lr & 7))) << 4) + ((lc & 7) << 1)) = (f16)v;
                }
            }
        }
        __syncthreads();
        const int col = tid & 63;
        const int rb  = tid >> 6;
        for (int rr = 0; rr < 32; ++rr) {
            int row = rb * 32 + rr;
            int g = rowmap[r0 + row];
            float e = (g >= 0) ? eps[(size_t)g * 64 + col] : 0.f;
            float mu = (float)*(const f16*)(smem + row * 256 + ((((col >> 3) ^ (row & 7))) << 4) + ((col & 7) << 1));
            int c2 = col + 64;
            float lv = (float)*(const f16*)(smem + row * 256 + ((((c2 >> 3) ^ (row & 7))) << 4) + ((c2 & 7) << 1));
            st_nt(&Out[(size_t)(r0 + row) * 64 + col], (f16)(mu + expf(0.5f * lv) * e));
        }
        return;
    }

    #pragma unroll
    for (int i = 0; i < 4; ++i) {
        #pragma unroll
        for (int r = 0; r < 4; ++r) {
            int orow = r0 + mb + i * 16 + quad * 4 + r;
            int g = 0;
            if (EPI == 1) g = rowmap[orow];
            #pragma unroll
            for (int j = 0; j < 4; ++j) {
                int ocol = n0 + nb + j * 16 + r16;
                float v = acc[i][j][r] + bv[j];
                if (RELU) v = fmaxf(v, 0.f);
                if (EPI == 1) {
                    if (g >= 0) st_nt(&OutF[(size_t)g * N + ocol], v);
                } else {
                    st_nt(&Out[(size_t)orow * N + ocol], (f16)v);
                }
            }
        }
    }
}

// ---------------- launch ----------------

extern "C" void kernel_launch(void* const* d_in, const int* in_sizes, int n_in,
                              void* d_out, int out_size, void* d_ws, size_t ws_size,
                              hipStream_t stream) {
    const float* x      = (const float*)d_in[0];
    const int*   lbl    = (const int*)  d_in[1];
    const float* eps    = (const float*)d_in[2];
    const float* enc_W0 = (const float*)d_in[3];
    const float* enc_b0 = (const float*)d_in[4];
    const float* enc_Wu = (const float*)d_in[5];
    const float* enc_bu = (const float*)d_in[6];
    const float* enc_W2 = (const float*)d_in[7];
    const float* enc_b2 = (const float*)d_in[8];
    const float* mu_W   = (const float*)d_in[9];
    const float* mu_b   = (const float*)d_in[10];
    const float* lv_W   = (const float*)d_in[11];
    const float* lv_b   = (const float*)d_in[12];
    const float* dWu0   = (const float*)d_in[13];
    const float* dbu0   = (const float*)d_in[14];
    const float* dW1    = (const float*)d_in[15];
    const float* db1    = (const float*)d_in[16];
    const float* dWu2   = (const float*)d_in[17];
    const float* dbu2   = (const float*)d_in[18];
    const float* finW   = (const float*)d_in[19];
    const float* finb   = (const float*)d_in[20];
    float* out = (float*)d_out;
    (void)in_sizes; (void)n_in; (void)out_size; (void)ws_size;

    char* base = (char*)d_ws;
    size_t off = 0;
    auto alloc = [&](size_t bytes) { char* r = base + off; off = (off + bytes + 255) & ~(size_t)255; return r; };
    f16* xh     = (f16*)alloc((size_t)B_ROWS * 512 * 2);
    f16* buf1   = (f16*)alloc((size_t)MPAD * 1024 * 2);  // h1 / h6
    f16* buf2   = (f16*)alloc((size_t)MPAD * 512 * 2);   // h2 / h5
    f16* buf3   = (f16*)alloc((size_t)MPAD * 256 * 2);   // h3 / h4
    f16* zb     = (f16*)alloc((size_t)MPAD * 64 * 2);
    f16* w0t    = (f16*)alloc(1024ul * 512 * 2);
    f16* wut    = (f16*)alloc(8ul * 512 * 1024 * 2);
    f16* w2t    = (f16*)alloc(256ul * 512 * 2);
    f16* wzt    = (f16*)alloc(128ul * 256 * 2);
    f16* wd0t   = (f16*)alloc(8ul * 256 * 64 * 2);
    f16* wd1t   = (f16*)alloc(512ul * 256 * 2);
    f16* wd2t   = (f16*)alloc(8ul * 1024 * 512 * 2);
    f16* wft    = (f16*)alloc(8ul * 512 * 1024 * 2);
    float* bz   = (float*)alloc(128 * 4);
    int* rowmap = (int*)alloc(MPAD * 4);
    int* blockhist = (int*)alloc(NBLK * 8 * 4);
    int* blockbase = (int*)alloc(NBLK * 8 * 4);
    int* offs   = (int*)alloc(64);
    int* tilec  = (int*)alloc(MTILES * 4);
    f16* zerob  = (f16*)alloc(256);

    // cluster sort + bias concat
    k_prep<<<MPAD / 256, 256, 0, stream>>>(lbl, blockhist, rowmap, mu_b, lv_b, bz, zerob);
    k_offsets<<<1, 256, 0, stream>>>(blockhist, offs, tilec, blockbase);
    k_scatter<<<NBLK, 256, 0, stream>>>(lbl, blockbase, rowmap);

    // merged convert + transposes, persistent 512-block grid
    SegTab tab;
    int b0 = B_ROWS * 512 / 8 / 256;   // 4096 cvt virtual blocks
    auto seg = [&](int i, const float* s, f16* d, int K, int N, int nz, long sCS, long dCS) {
        int nx = N / 64, ny = K / 64;
        tab.g[i] = Seg{s, d, K, N, b0, nx, ny, sCS, dCS};
        b0 += nx * ny * nz;
    };
    tab.g[0] = Seg{nullptr, nullptr, 0, 0, 0, 0, 0, 0, 0};
    seg(1, enc_W0, w0t, 512, 1024, 1, 0, 0);
    seg(2, enc_Wu, wut, 1024, 512, 8, 1024l * 512, 512l * 1024);
    seg(3, enc_W2, w2t, 512, 256, 1, 0, 0);
    seg(4, mu_W, wzt, 256, 64, 1, 0, 0);
    seg(5, lv_W, wzt + 64 * 256, 256, 64, 1, 0, 0);
    seg(6, dWu0, wd0t, 64, 256, 8, 64l * 256, 256l * 64);
    seg(7, dW1, wd1t, 256, 512, 1, 0, 0);
    seg(8, dWu2, wd2t, 512, 1024, 8, 512l * 1024, 1024l * 512);
    seg(9, finW, wft, 1024, 512, 8, 1024l * 512, 512l * 1024);
    k_trans<<<512, 256, 0, stream>>>(tab, x, xh, b0);

    // encoder
    gemm2_k<1,0><<<MTILES * 4, 512, 0, stream>>>(xh,   w0t,  enc_b0, buf1, rowmap, tilec, zerob, 512, 1024);
    gemm_k<0,1,1,0><<<MTILES * 4, 256, 0, stream>>>(buf1, wut,  enc_bu, buf2, nullptr, nullptr, rowmap, tilec, zerob, 1024, 512);
    gemm_k<0,0,1,0><<<MTILES * 2, 256, 0, stream>>>(buf2, w2t,  enc_b2, buf3, nullptr, nullptr, rowmap, tilec, zerob, 512, 256);
    // latent heads (mu|logvar fused, no relu) + in-kernel reparameterize -> z
    gemm_k<0,0,0,2><<<MTILES * 1, 256, 0, stream>>>(buf3, wzt,  bz,     zb,   nullptr, eps,     rowmap, tilec, zerob, 256, 128);
    // decoder
    gemm_k<0,1,1,0><<<MTILES * 2, 256, 0, stream>>>(zb,   wd0t, dbu0,   buf3, nullptr, nullptr, rowmap, tilec, zerob, 64, 256);
    gemm_k<0,0,1,0><<<MTILES * 4, 256, 0, stream>>>(buf3, wd1t, db1,    buf2, nullptr, nullptr, rowmap, tilec, zerob, 256, 512);
    gemm2_k<0,1><<<MTILES * 4, 512, 0, stream>>>(buf2, wd2t, dbu2,   buf1, rowmap, tilec, zerob, 512, 1024);
    // final per-cluster layer, fp32 scatter to d_out
    gemm_k<0,1,0,1><<<MTILES * 4, 256, 0, stream>>>(buf1, wft,  finb,   nullptr, out,  nullptr, rowmap, tilec, zerob, 1024, 512);
}